// Round 3
// baseline (2144.446 us; speedup 1.0000x reference)
//
#include <hip/hip_runtime.h>
#include <math.h>

// Problem constants (fixed by the reference setup)
#define NTOK  65536      // B*T = 16*4096
#define DDIM  256
#define KCODE 1024
#define LLAY  8
#define NQ    (NTOK*DDIM)        // 16777216 floats: quantized output
#define LOSS_OFF NQ              // 1 float: total loss
#define IDX_OFF  (NQ+1)          // 524288 floats: indices [B,T,L] as float

// ws layout (bytes):
//   [0, 4MB)     E_hi  bf16, SWIZZLED into MFMA B-fragment order:
//                element (((l*64 + t)*8 + ks)*64 + lane)*8 + j
//                  = Ehi_linear[l][t*16 + (lane&15)][ks*32 + (lane>>4)*8 + j]
//   [4MB, 8MB)   E_lo  bf16, same swizzle
//   [8MB, +32KB) ekk   f32  [l][k]  = ||e||^2 (f64-accumulated, narrowed)
#define EHI_OFF 0
#define ELO_OFF (LLAY*KCODE*DDIM)          // in ushort elements: 2097152
#define EKK_BYTE_OFF 8388608

typedef __attribute__((ext_vector_type(8))) short short8;   // 8 bf16 (4 VGPR)
typedef __attribute__((ext_vector_type(4))) float f32x4;    // MFMA C/D frag

__device__ __forceinline__ unsigned short f2bf(float f) {   // RTNE f32->bf16
    unsigned u = __float_as_uint(f);
    u = u + 0x7fffu + ((u >> 16) & 1u);
    return (unsigned short)(u >> 16);
}
__device__ __forceinline__ float bf2f(unsigned short h) {
    return __uint_as_float(((unsigned)h) << 16);
}

// ---------------------------------------------------------------------------
// Prep kernel A: split E f32 -> bf16 hi/lo, written in swizzled MFMA
// B-fragment order so the main kernel's loads are fully coalesced streams.
// ---------------------------------------------------------------------------
__global__ __launch_bounds__(256) void rvq_prep_swz(const float* __restrict__ E,
                                                    unsigned short* __restrict__ Ehi,
                                                    unsigned short* __restrict__ Elo,
                                                    float* __restrict__ out) {
    int gid  = blockIdx.x * 256 + threadIdx.x;   // 1024 blocks * 256
    int lane = gid & 63;
    int ks   = (gid >> 6) & 7;
    int t    = (gid >> 9) & 63;
    int l    = gid >> 15;
    int code = t * 16 + (lane & 15);
    int d    = ks * 32 + (lane >> 4) * 8;
    const float* src = E + ((size_t)(l * KCODE + code)) * DDIM + d;
    float4 a = *(const float4*)(src);
    float4 b = *(const float4*)(src + 4);
    float f[8] = {a.x, a.y, a.z, a.w, b.x, b.y, b.z, b.w};
    short8 h, lo;
#pragma unroll
    for (int j = 0; j < 8; ++j) {
        unsigned short hh = f2bf(f[j]);
        h[j]  = (short)hh;
        lo[j] = (short)f2bf(f[j] - bf2f(hh));
    }
    *(short8*)(Ehi + (size_t)gid * 8) = h;
    *(short8*)(Elo + (size_t)gid * 8) = lo;
    if (gid == 0) out[LOSS_OFF] = 0.0f;
}

// ---------------------------------------------------------------------------
// Prep kernel B: per-code ||e||^2 (f32 squares, f64 accumulate, narrow).
// ---------------------------------------------------------------------------
__global__ __launch_bounds__(256) void rvq_ekk(const float* __restrict__ E,
                                               float* __restrict__ ekk) {
    int gid = blockIdx.x * 256 + threadIdx.x;   // 8192 = L*K
    const float4* rowp = (const float4*)(E + (size_t)gid * DDIM);
    double s = 0.0;
#pragma unroll 8
    for (int i = 0; i < 64; ++i) {
        float4 v = rowp[i];
        float p0 = v.x * v.x, p1 = v.y * v.y, p2 = v.z * v.z, p3 = v.w * v.w;
        s += (double)p0; s += (double)p1; s += (double)p2; s += (double)p3;
    }
    ekk[gid] = (float)s;
}

// ---------------------------------------------------------------------------
// top-2 merge with (score, index) lexicographic order (np.argmin ties)
// ---------------------------------------------------------------------------
__device__ __forceinline__ void merge2(float& s1, int& k1, float& s2, int& k2,
                                       float ps1, int pk1, float ps2, int pk2) {
    bool pb = (ps1 < s1) || (ps1 == s1 && pk1 < k1);
    if (pb) {
        bool mb = (s1 < ps2) || (s1 == ps2 && k1 < pk2);
        float ns2 = mb ? s1 : ps2; int nk2 = mb ? k1 : pk2;
        s1 = ps1; k1 = pk1; s2 = ns2; k2 = nk2;
    } else {
        bool mb = (ps1 < s2) || (ps1 == s2 && pk1 < k2);
        if (mb) { s2 = ps1; k2 = pk1; }
    }
}

// ---------------------------------------------------------------------------
// Main kernel: 64 tokens/block, 512 threads = 8 waves.
//   wave wv: token-quarter tq=wv&3 (16 tokens, ONE MFMA tile),
//            code-half ch=wv>>2 (512 codes).
//   Per-wave register demand ~120 VGPR (A-cache 64, B-rotation 32, top-2 24)
//   so __launch_bounds__(512,4) caps at 128 spill-free -> 2 blocks/CU.
//   Numerics bitwise-identical to the 4-wave version: per-accumulator MFMA
//   order, candidate sets, exact rescore, update and loss-sum order unchanged
//   (serial phases run on tid<256 with the identical old thread mapping).
// ---------------------------------------------------------------------------
__global__ __launch_bounds__(512, 4) void rvq_main(const float* __restrict__ x,
                                                   const float* __restrict__ E,
                                                   const unsigned short* __restrict__ Ehi,
                                                   const unsigned short* __restrict__ Elo,
                                                   const float* __restrict__ ekk,
                                                   float* __restrict__ out) {
    __shared__ __align__(16) float  Rt[64 * 260];   // residual f32 [tok][260pad]
    __shared__ double Ad[256];                      // A_n partial sums
    __shared__ float4 cand[128];                    // [tok][ch]: s1,k1,s2,k2
    __shared__ float  Af[64];                       // per-token ||r||^2 (f32)
    __shared__ int    kw[64];                       // winning code per token
    __shared__ float  lred[8];                      // per-wave loss partials

    const int tid  = threadIdx.x;
    const int lane = tid & 63;
    const int wv   = tid >> 6;     // 0..7
    const int tq   = wv & 3;       // token quarter (16 tokens = 1 MFMA tile)
    const int ch   = wv >> 2;      // code half
    const int col  = lane & 15;    // MFMA n / m index within tile
    const int quad = lane >> 4;    // MFMA k-chunk selector
    const int m0   = blockIdx.x * 64;

    // ---- load residual = x into LDS (row-major, pad 260) ----
#pragma unroll
    for (int u = 0; u < 8; ++u) {
        int id4 = u * 512 + tid;          // 4096 float4
        int mm  = id4 >> 6;
        int d4  = (id4 & 63) << 2;
        float4 v = *(const float4*)(x + (size_t)(m0 + mm) * DDIM + d4);
        *(float4*)(&Rt[mm * 260 + d4]) = v;
    }

    float lacc = 0.f;

    for (int l = 0; l < LLAY; ++l) {
        const float* El = E + (size_t)l * KCODE * DDIM;
        __syncthreads();   // Rt stable (prev layer update done)

        // ---- A_m = sum_d fl32(r^2), f64-accurate, narrowed to f32 ----
        if (tid < 256) {
            int m = tid >> 2, c = tid & 3;
            const float* rr = &Rt[m * 260 + c * 64];
            double sa = 0.0;
#pragma unroll 4
            for (int q = 0; q < 16; ++q) {
                float4 v = *(const float4*)(rr + q * 4);
                float p0 = v.x * v.x, p1 = v.y * v.y, p2 = v.z * v.z, p3 = v.w * v.w;
                sa += (double)p0; sa += (double)p1; sa += (double)p2; sa += (double)p3;
            }
            Ad[tid] = sa;
        }
        __syncthreads();
        if (tid < 64) {
            double a = Ad[tid * 4] + Ad[tid * 4 + 1] + Ad[tid * 4 + 2] + Ad[tid * 4 + 3];
            Af[tid] = (float)a;
        }
        __syncthreads();

        // ---- per-lane A values for the 4 accumulator rows of this tile ----
        float Ai[4];
#pragma unroll
        for (int g = 0; g < 4; ++g)
            Ai[g] = Af[tq * 16 + quad * 4 + g];

        // ---- build A-frag cache (bf16 hi/lo) for this wave's 16 tokens ----
        short8 ah[8], al[8];
        {
            const float* rrow = &Rt[(tq * 16 + col) * 260];
#pragma unroll
            for (int ks = 0; ks < 8; ++ks) {
                float4 p = *(const float4*)(rrow + ks * 32 + quad * 8);
                float4 q = *(const float4*)(rrow + ks * 32 + quad * 8 + 4);
                float f[8] = {p.x, p.y, p.z, p.w, q.x, q.y, q.z, q.w};
#pragma unroll
                for (int j = 0; j < 8; ++j) {
                    unsigned short h = f2bf(f[j]);
                    ah[ks][j] = (short)h;
                    al[ks][j] = (short)f2bf(f[j] - bf2f(h));
                }
            }
        }

        // ---- approx scoring: 32 code-tiles of 16, top-2 per lane-stream ----
        // tp[g] packs (tc2<<8 | tc1); tile-codes are 5-bit, 0xff = sentinel.
        float ts1[4], ts2[4];
        int   tp[4];
#pragma unroll
        for (int g = 0; g < 4; ++g) {
            ts1[g] = INFINITY; ts2[g] = INFINITY; tp[g] = 0xffff;
        }

        const int co = ch * 512;
        // linear swizzled stream: step = c*8 + ks, 512 ushorts (1KB) per step
        const unsigned short* ph =
            Ehi + ((size_t)(l * 64 + ch * 32) * 4096) + (size_t)lane * 8;
        const unsigned short* pl =
            Elo + ((size_t)(l * 64 + ch * 32) * 4096) + (size_t)lane * 8;
        const float* ekbase = ekk + l * KCODE + co + col;

        // 4-slot rotation, 3-step prefetch lead. Slot (s%4) holds step s.
        short8 BH[4], BL[4];
        BH[0] = *(const short8*)(ph);           BL[0] = *(const short8*)(pl);
        BH[1] = *(const short8*)(ph + 512);     BL[1] = *(const short8*)(pl + 512);
        BH[2] = *(const short8*)(ph + 1024);    BL[2] = *(const short8*)(pl + 1024);

        for (int c = 0; c < 32; ++c) {
            float ekv = ekbase[c * 16];

            f32x4 acc = {0.f, 0.f, 0.f, 0.f};
#pragma unroll
            for (int ks = 0; ks < 8; ++ks) {
                const int pf = (ks + 3) & 3;     // prefetch slot (compile-time)
                const int cs = ks & 3;           // consume slot (compile-time)
                // worst-case 3KB tail overrun stays inside allocated ws
                BH[pf] = *(const short8*)(ph + (ks + 3) * 512);
                BL[pf] = *(const short8*)(pl + (ks + 3) * 512);
                acc = __builtin_amdgcn_mfma_f32_16x16x32_bf16(ah[ks], BH[cs], acc, 0, 0, 0);
                acc = __builtin_amdgcn_mfma_f32_16x16x32_bf16(ah[ks], BL[cs], acc, 0, 0, 0);
                acc = __builtin_amdgcn_mfma_f32_16x16x32_bf16(al[ks], BH[cs], acc, 0, 0, 0);
            }
            ph += 4096; pl += 4096;

#pragma unroll
            for (int g = 0; g < 4; ++g) {
                float s = fmaf(-2.f, acc[g], Ai[g] + ekv);
                if (s < ts1[g]) {
                    ts2[g] = ts1[g];
                    tp[g]  = ((tp[g] & 0xff) << 8) | c;
                    ts1[g] = s;
                } else if (s < ts2[g]) {
                    ts2[g] = s;
                    tp[g]  = (tp[g] & 0xff) | (c << 8);
                }
            }
        }

        // ---- convert tile-codes to global code indices ----
        int ik1[4], ik2[4];
#pragma unroll
        for (int g = 0; g < 4; ++g) {
            ik1[g] = co + ((tp[g] & 0xff) << 4) + col;
            ik2[g] = co + (((tp[g] >> 8) & 0xff) << 4) + col;
        }

        // ---- merge top-2 across the 16 cols (lanes differing in bits 0..3) ----
#pragma unroll
        for (int off = 1; off <= 8; off <<= 1) {
#pragma unroll
            for (int g = 0; g < 4; ++g) {
                float os1 = __shfl_xor(ts1[g], off, 64);
                int   ok1 = __shfl_xor(ik1[g], off, 64);
                float os2 = __shfl_xor(ts2[g], off, 64);
                int   ok2 = __shfl_xor(ik2[g], off, 64);
                merge2(ts1[g], ik1[g], ts2[g], ik2[g], os1, ok1, os2, ok2);
            }
        }
        if (col == 0) {
#pragma unroll
            for (int g = 0; g < 4; ++g) {
                int tokl = tq * 16 + quad * 4 + g;
                cand[tokl * 2 + ch] = make_float4(ts1[g], __int_as_float(ik1[g]),
                                                  ts2[g], __int_as_float(ik2[g]));
            }
        }
        __syncthreads();

        // ---- exact f32 rescore of the 4 candidates (bitwise np semantics) ----
        if (tid < 256) {
            int m = tid >> 2, j = tid & 3;
            float4 cd = cand[m * 2 + (j >> 1)];
            int myk = (j & 1) ? __float_as_int(cd.w) : __float_as_int(cd.y);
            const float* erow = El + (size_t)myk * DDIM;
            const float* rrow = &Rt[m * 260];
            float M = 0.f;
#pragma unroll 8
            for (int q = 0; q < 64; ++q) {     // ascending-d single fma chain
                float4 e4 = *(const float4*)(erow + q * 4);
                float4 r4 = *(const float4*)(rrow + q * 4);
                M = fmaf(r4.x, e4.x, M);
                M = fmaf(r4.y, e4.y, M);
                M = fmaf(r4.z, e4.z, M);
                M = fmaf(r4.w, e4.w, M);
            }
            float u = Af[m] + ekk[l * KCODE + myk];   // fl32(A + B)
            float s = fmaf(-2.f, M, u);               // fl32(u - 2M)
#pragma unroll
            for (int off = 1; off <= 2; off <<= 1) {
                float os = __shfl_xor(s, off, 64);
                int   ok = __shfl_xor(myk, off, 64);
                if ((os < s) || (os == s && ok < myk)) { s = os; myk = ok; }
            }
            if (j == 0) {
                kw[m] = myk;
                out[IDX_OFF + (size_t)(m0 + m) * LLAY + l] = (float)myk;
            }
        }
        __syncthreads();

        // ---- residual update (exact straight-through f32 ops) + loss ----
        if (tid < 256) {
            int m  = tid >> 2;
            int ds = (tid & 3) * 64;
            int kwm = kw[m];
            const float* erow = El + (size_t)kwm * DDIM;
            const float* xrow = x  + (size_t)(m0 + m) * DDIM;
            float*       orow = out + (size_t)(m0 + m) * DDIM;
            float*       rrow = &Rt[m * 260];
#pragma unroll 4
            for (int q = 0; q < 16; ++q) {
                int d = ds + q * 4;
                float4 e4 = *(const float4*)(erow + d);
                float4 r4 = *(const float4*)(rrow + d);
                float qv[4] = {e4.x, e4.y, e4.z, e4.w};
                float rv[4] = {r4.x, r4.y, r4.z, r4.w};
                float rn[4];
#pragma unroll
                for (int t = 0; t < 4; ++t) {
                    float d1  = qv[t] - rv[t];   // fl(q - r)  (loss term)
                    float qst = rv[t] + d1;      // fl(r + d1) (straight-through)
                    rn[t]     = rv[t] - qst;     // fl(r - q_st)
                    lacc = fmaf(d1, d1, lacc);
                }
                *(float4*)(rrow + d) = make_float4(rn[0], rn[1], rn[2], rn[3]);
                if (l == LLAY - 1) {
                    float4 x4 = *(const float4*)(xrow + d);
                    *(float4*)(orow + d) =
                        make_float4(x4.x - rn[0], x4.y - rn[1], x4.z - rn[2], x4.w - rn[3]);
                }
            }
        }
    }

    // ---- loss reduction: wave -> block -> global atomic ----
    // waves 4..7 carry exact 0.0f; adding them preserves the old sum bitwise.
#pragma unroll
    for (int off = 32; off > 0; off >>= 1) lacc += __shfl_down(lacc, off, 64);
    __syncthreads();
    if ((tid & 63) == 0) lred[tid >> 6] = lacc;
    __syncthreads();
    if (tid == 0) {
        float t = ((((((lred[0] + lred[1]) + lred[2]) + lred[3]) + lred[4])
                    + lred[5]) + lred[6]) + lred[7];
        atomicAdd(out + LOSS_OFF, t * (0.25f / 16777216.0f));
    }
}

// ---------------------------------------------------------------------------
extern "C" void kernel_launch(void* const* d_in, const int* in_sizes, int n_in,
                              void* d_out, int out_size, void* d_ws, size_t ws_size,
                              hipStream_t stream) {
    const float* x  = (const float*)d_in[0];
    const float* E  = (const float*)d_in[1];
    float* out = (float*)d_out;
    unsigned short* Ehi = (unsigned short*)d_ws;
    unsigned short* Elo = Ehi + ELO_OFF;
    float* ekkp = (float*)((char*)d_ws + EKK_BYTE_OFF);   // needs ~8.42 MB ws

    rvq_prep_swz<<<dim3(1024), dim3(256), 0, stream>>>(E, Ehi, Elo, out);
    rvq_ekk<<<dim3(32), dim3(256), 0, stream>>>(E, ekkp);
    rvq_main<<<dim3(1024), dim3(512), 0, stream>>>(x, E, Ehi, Elo, ekkp, out);
}

// Round 4
// 1913.630 us; speedup vs baseline: 1.1206x; 1.1206x over previous
//
#include <hip/hip_runtime.h>
#include <math.h>

// Problem constants (fixed by the reference setup)
#define NTOK  65536      // B*T = 16*4096
#define DDIM  256
#define KCODE 1024
#define LLAY  8
#define NQ    (NTOK*DDIM)        // 16777216 floats: quantized output
#define LOSS_OFF NQ              // 1 float: total loss
#define IDX_OFF  (NQ+1)          // 524288 floats: indices [B,T,L] as float

// ws layout (bytes):
//   [0, 4MB)     Eh16: f16 (hi) codebook, SWIZZLED into MFMA B-fragment order:
//                element (((l*64 + t)*8 + ks)*64 + lane)*8 + j
//                  = E[l][t*16 + (lane&15)][ks*32 + (lane>>4)*8 + j]  (f16 RTNE)
//   [8MB, +32KB) ekk   f32  [l][k]  = ||e||^2 (f64-accumulated, narrowed)
#define EKK_BYTE_OFF 8388608

typedef __attribute__((ext_vector_type(8))) _Float16 half8;  // 8 f16 (4 VGPR)
typedef __attribute__((ext_vector_type(4))) float f32x4;     // MFMA C/D frag

// ---------------------------------------------------------------------------
// Prep kernel A: E f32 -> f16 (hi only), swizzled MFMA B-fragment order.
// One thread per (l, t, ks, lane): 8*64*8*64 = 262144 threads.
// ---------------------------------------------------------------------------
__global__ __launch_bounds__(256) void rvq_prep16(const float* __restrict__ E,
                                                  _Float16* __restrict__ Eh,
                                                  float* __restrict__ out) {
    int gid  = blockIdx.x * 256 + threadIdx.x;   // 1024 blocks * 256
    int lane = gid & 63;
    int ks   = (gid >> 6) & 7;
    int t    = (gid >> 9) & 63;
    int l    = gid >> 15;
    int code = t * 16 + (lane & 15);
    int d    = ks * 32 + (lane >> 4) * 8;
    const float* src = E + ((size_t)(l * KCODE + code)) * DDIM + d;
    float4 a = *(const float4*)(src);
    float4 b = *(const float4*)(src + 4);
    float f[8] = {a.x, a.y, a.z, a.w, b.x, b.y, b.z, b.w};
    half8 h;
#pragma unroll
    for (int j = 0; j < 8; ++j) h[j] = (_Float16)f[j];   // RTNE
    *(half8*)(Eh + (size_t)gid * 8) = h;
    if (gid == 0) out[LOSS_OFF] = 0.0f;
}

// ---------------------------------------------------------------------------
// Prep kernel B: per-code ||e||^2 (f32 squares, f64 accumulate, narrow).
// ---------------------------------------------------------------------------
__global__ __launch_bounds__(256) void rvq_ekk(const float* __restrict__ E,
                                               float* __restrict__ ekk) {
    int gid = blockIdx.x * 256 + threadIdx.x;   // 8192 = L*K
    const float4* rowp = (const float4*)(E + (size_t)gid * DDIM);
    double s = 0.0;
#pragma unroll 8
    for (int i = 0; i < 64; ++i) {
        float4 v = rowp[i];
        float p0 = v.x * v.x, p1 = v.y * v.y, p2 = v.z * v.z, p3 = v.w * v.w;
        s += (double)p0; s += (double)p1; s += (double)p2; s += (double)p3;
    }
    ekk[gid] = (float)s;
}

// ---------------------------------------------------------------------------
// top-2 merge with (score, index) lexicographic order (np.argmin ties)
// ---------------------------------------------------------------------------
__device__ __forceinline__ void merge2(float& s1, int& k1, float& s2, int& k2,
                                       float ps1, int pk1, float ps2, int pk2) {
    bool pb = (ps1 < s1) || (ps1 == s1 && pk1 < k1);
    if (pb) {
        bool mb = (s1 < ps2) || (s1 == ps2 && k1 < pk2);
        float ns2 = mb ? s1 : ps2; int nk2 = mb ? k1 : pk2;
        s1 = ps1; k1 = pk1; s2 = ns2; k2 = nk2;
    } else {
        bool mb = (ps1 < s2) || (ps1 == s2 && pk1 < k2);
        if (mb) { s2 = ps1; k2 = pk1; }
    }
}

// ---------------------------------------------------------------------------
// Main kernel: 64 tokens/block, 512 threads = 8 waves.
//   wave wv: th = wv&1 (token half: 2 MFMA tiles), ch = (wv>>1)&1 (code half),
//            cpar = wv>>2 (c-tile parity). Each wave scores 2 tiles x 16
//            c-tiles with SINGLE-PASS f16 MFMA (error ~2e-6 << approx-score
//            gaps ~3e-3; exact f32 rescore of candidates decides bitwise).
//   B-fragments are staged tile-by-tile into LDS via global_load_lds
//   (double-buffered; each wave stages 2 x 1KB segments per c-step), shared
//   across waves -> global B traffic drops 17GB -> 4.2GB (was L3-BW-bound).
//   Candidates: top-2 per (ch,cpar) merged pairwise to top-2 per ch ->
//   bitwise-identical candidate set and winner as the 3-pass version.
// ---------------------------------------------------------------------------
__global__ __launch_bounds__(512, 2) void rvq_main(const float* __restrict__ x,
                                                   const float* __restrict__ E,
                                                   const _Float16* __restrict__ Eh,
                                                   const float* __restrict__ ekk,
                                                   float* __restrict__ out) {
    __shared__ __align__(16) float  Rt[64 * 260];   // residual f32 [tok][260pad]
    __shared__ double Ad[256];                      // A_n partial sums
    __shared__ __align__(16) float4 cand[64 * 4];   // [tok][ch*2+cpar]
    __shared__ __align__(16) float4 cand2[64 * 2];  // [tok][ch] merged
    __shared__ float  Af[64];                       // per-token ||r||^2 (f32)
    __shared__ int    kw[64];                       // winning code per token
    __shared__ float  lred[8];                      // per-wave loss partials
    __shared__ __align__(16) _Float16 Bs[2][2][8][512];  // [buf][ch][ks][lane*8]

    const int tid  = threadIdx.x;
    const int lane = tid & 63;
    const int wv   = tid >> 6;       // 0..7
    const int th   = wv & 1;         // token half (2 tiles)
    const int ch   = (wv >> 1) & 1;  // code half
    const int cpar = wv >> 2;        // c-tile parity this wave computes
    const int col  = lane & 15;
    const int quad = lane >> 4;
    const int m0   = blockIdx.x * 64;
    const int segch = cpar;          // staging: code-half this wave stages
    const int ks0   = (wv & 3) * 2;  // staging: ks pair this wave stages

    // ---- load residual = x into LDS (row-major, pad 260) ----
#pragma unroll
    for (int u = 0; u < 8; ++u) {
        int id4 = u * 512 + tid;          // 4096 float4
        int mm  = id4 >> 6;
        int d4  = (id4 & 63) << 2;
        float4 v = *(const float4*)(x + (size_t)(m0 + mm) * DDIM + d4);
        *(float4*)(&Rt[mm * 260 + d4]) = v;
    }

    float lacc = 0.f;

    // ---- stage (l=0, c=0) into buf 0 ----
    {
        const _Float16* g0 = Eh + ((size_t)((segch * 32) * 4096) + ks0 * 512)
                              + (size_t)lane * 8;
        _Float16* d0 = &Bs[0][segch][ks0][0];
        __builtin_amdgcn_global_load_lds(
            (const __attribute__((address_space(1))) unsigned int*)g0,
            (__attribute__((address_space(3))) unsigned int*)d0, 16, 0, 0);
        __builtin_amdgcn_global_load_lds(
            (const __attribute__((address_space(1))) unsigned int*)(g0 + 512),
            (__attribute__((address_space(3))) unsigned int*)(d0 + 512), 16, 0, 0);
    }

    for (int l = 0; l < LLAY; ++l) {
        const float* El = E + (size_t)l * KCODE * DDIM;
        __syncthreads();   // Rt stable; staged buf0 landed (barrier drains vmcnt)

        // ---- A_m = sum_d fl32(r^2), f64-accurate, narrowed to f32 ----
        if (tid < 256) {
            int m = tid >> 2, c = tid & 3;
            const float* rr = &Rt[m * 260 + c * 64];
            double sa = 0.0;
#pragma unroll 4
            for (int q = 0; q < 16; ++q) {
                float4 v = *(const float4*)(rr + q * 4);
                float p0 = v.x * v.x, p1 = v.y * v.y, p2 = v.z * v.z, p3 = v.w * v.w;
                sa += (double)p0; sa += (double)p1; sa += (double)p2; sa += (double)p3;
            }
            Ad[tid] = sa;
        }
        __syncthreads();
        if (tid < 64) {
            double a = Ad[tid * 4] + Ad[tid * 4 + 1] + Ad[tid * 4 + 2] + Ad[tid * 4 + 3];
            Af[tid] = (float)a;
        }
        __syncthreads();

        // ---- per-lane A values for the 8 (tile,reg) accumulator rows ----
        float Ai[2][4];
#pragma unroll
        for (int tt = 0; tt < 2; ++tt)
#pragma unroll
            for (int g = 0; g < 4; ++g)
                Ai[tt][g] = Af[th * 32 + tt * 16 + quad * 4 + g];

        // ---- build A-frag cache (f16 hi) for this wave's 2 tiles ----
        half8 ah[2][8];
#pragma unroll
        for (int tt = 0; tt < 2; ++tt) {
            const float* rrow = &Rt[(th * 32 + tt * 16 + col) * 260];
#pragma unroll
            for (int ks = 0; ks < 8; ++ks) {
                float4 p = *(const float4*)(rrow + ks * 32 + quad * 8);
                float4 q = *(const float4*)(rrow + ks * 32 + quad * 8 + 4);
                float f[8] = {p.x, p.y, p.z, p.w, q.x, q.y, q.z, q.w};
#pragma unroll
                for (int j = 0; j < 8; ++j) ah[tt][ks][j] = (_Float16)f[j];
            }
        }

        // ---- approx scoring over this wave's 16 c-tiles (parity cpar) ----
        float ts1[2][4], ts2[2][4];
        int   tp[2][4];                      // packed (tc2<<8 | tc1)
#pragma unroll
        for (int tt = 0; tt < 2; ++tt)
#pragma unroll
            for (int g = 0; g < 4; ++g) {
                ts1[tt][g] = INFINITY; ts2[tt][g] = INFINITY; tp[tt][g] = 0xffff;
            }

        const int co = ch * 512;
        const float* ekbase = ekk + l * KCODE + co + col;

        for (int c = 0; c < 32; ++c) {
            // stage next tile (next c, or next layer's c=0) into the other buf
            int nl = l, nc = c + 1;
            if (nc == 32) { nl = l + 1; nc = 0; }
            if (nl < LLAY) {
                const _Float16* g0 = Eh
                    + ((size_t)((nl * 64 + segch * 32 + nc) * 4096) + ks0 * 512)
                    + (size_t)lane * 8;
                _Float16* d0 = &Bs[nc & 1][segch][ks0][0];
                __builtin_amdgcn_global_load_lds(
                    (const __attribute__((address_space(1))) unsigned int*)g0,
                    (__attribute__((address_space(3))) unsigned int*)d0, 16, 0, 0);
                __builtin_amdgcn_global_load_lds(
                    (const __attribute__((address_space(1))) unsigned int*)(g0 + 512),
                    (__attribute__((address_space(3))) unsigned int*)(d0 + 512), 16, 0, 0);
            }

            if ((c & 1) == cpar) {
                float ekv = ekbase[c * 16];
                f32x4 acc0 = {0.f, 0.f, 0.f, 0.f};
                f32x4 acc1 = {0.f, 0.f, 0.f, 0.f};
#pragma unroll
                for (int ks = 0; ks < 8; ++ks) {
                    half8 bh = *(const half8*)(&Bs[c & 1][ch][ks][lane * 8]);
                    acc0 = __builtin_amdgcn_mfma_f32_16x16x32_f16(ah[0][ks], bh, acc0, 0, 0, 0);
                    acc1 = __builtin_amdgcn_mfma_f32_16x16x32_f16(ah[1][ks], bh, acc1, 0, 0, 0);
                }
#pragma unroll
                for (int tt = 0; tt < 2; ++tt)
#pragma unroll
                    for (int g = 0; g < 4; ++g) {
                        float v = tt ? acc1[g] : acc0[g];
                        float s = fmaf(-2.f, v, Ai[tt][g] + ekv);
                        if (s < ts1[tt][g]) {
                            ts2[tt][g] = ts1[tt][g];
                            tp[tt][g]  = ((tp[tt][g] & 0xff) << 8) | c;
                            ts1[tt][g] = s;
                        } else if (s < ts2[tt][g]) {
                            ts2[tt][g] = s;
                            tp[tt][g]  = (tp[tt][g] & 0xff) | (c << 8);
                        }
                    }
            }
            // barrier: (a) staged loads for next buf landed (drains vmcnt);
            // (b) everyone's reads of buf[c&1] done before it is re-staged.
            __syncthreads();
        }

        // ---- convert tile-codes to global code indices ----
        int ik1[2][4], ik2[2][4];
#pragma unroll
        for (int tt = 0; tt < 2; ++tt)
#pragma unroll
            for (int g = 0; g < 4; ++g) {
                ik1[tt][g] = co + ((tp[tt][g] & 0xff) << 4) + col;
                ik2[tt][g] = co + (((tp[tt][g] >> 8) & 0xff) << 4) + col;
            }

        // ---- merge top-2 across the 16 cols ----
#pragma unroll
        for (int off = 1; off <= 8; off <<= 1) {
#pragma unroll
            for (int tt = 0; tt < 2; ++tt)
#pragma unroll
                for (int g = 0; g < 4; ++g) {
                    float os1 = __shfl_xor(ts1[tt][g], off, 64);
                    int   ok1 = __shfl_xor(ik1[tt][g], off, 64);
                    float os2 = __shfl_xor(ts2[tt][g], off, 64);
                    int   ok2 = __shfl_xor(ik2[tt][g], off, 64);
                    merge2(ts1[tt][g], ik1[tt][g], ts2[tt][g], ik2[tt][g],
                           os1, ok1, os2, ok2);
                }
        }
        if (col == 0) {
#pragma unroll
            for (int tt = 0; tt < 2; ++tt)
#pragma unroll
                for (int g = 0; g < 4; ++g) {
                    int tokl = th * 32 + tt * 16 + quad * 4 + g;
                    cand[tokl * 4 + ch * 2 + cpar] =
                        make_float4(ts1[tt][g], __int_as_float(ik1[tt][g]),
                                    ts2[tt][g], __int_as_float(ik2[tt][g]));
                }
        }
        __syncthreads();

        // ---- merge the two parities -> top-2 per code-half (old cand set) ----
        if (tid < 128) {
            int m = tid >> 1, hh = tid & 1;
            float4 a = cand[m * 4 + hh * 2 + 0];
            float4 b = cand[m * 4 + hh * 2 + 1];
            float s1 = a.x; int k1 = __float_as_int(a.y);
            float s2 = a.z; int k2 = __float_as_int(a.w);
            merge2(s1, k1, s2, k2, b.x, __float_as_int(b.y), b.z, __float_as_int(b.w));
            cand2[m * 2 + hh] = make_float4(s1, __int_as_float(k1),
                                            s2, __int_as_float(k2));
        }
        __syncthreads();

        // ---- exact f32 rescore of the 4 candidates (bitwise np semantics) ----
        if (tid < 256) {
            int m = tid >> 2, j = tid & 3;
            float4 cd = cand2[m * 2 + (j >> 1)];
            int myk = (j & 1) ? __float_as_int(cd.w) : __float_as_int(cd.y);
            const float* erow = El + (size_t)myk * DDIM;
            const float* rrow = &Rt[m * 260];
            float M = 0.f;
#pragma unroll 8
            for (int q = 0; q < 64; ++q) {     // ascending-d single fma chain
                float4 e4 = *(const float4*)(erow + q * 4);
                float4 r4 = *(const float4*)(rrow + q * 4);
                M = fmaf(r4.x, e4.x, M);
                M = fmaf(r4.y, e4.y, M);
                M = fmaf(r4.z, e4.z, M);
                M = fmaf(r4.w, e4.w, M);
            }
            float u = Af[m] + ekk[l * KCODE + myk];   // fl32(A + B)
            float s = fmaf(-2.f, M, u);               // fl32(u - 2M)
#pragma unroll
            for (int off = 1; off <= 2; off <<= 1) {
                float os = __shfl_xor(s, off, 64);
                int   ok = __shfl_xor(myk, off, 64);
                if ((os < s) || (os == s && ok < myk)) { s = os; myk = ok; }
            }
            if (j == 0) {
                kw[m] = myk;
                out[IDX_OFF + (size_t)(m0 + m) * LLAY + l] = (float)myk;
            }
        }
        __syncthreads();

        // ---- residual update (exact straight-through f32 ops) + loss ----
        if (tid < 256) {
            int m  = tid >> 2;
            int ds = (tid & 3) * 64;
            int kwm = kw[m];
            const float* erow = El + (size_t)kwm * DDIM;
            const float* xrow = x  + (size_t)(m0 + m) * DDIM;
            float*       orow = out + (size_t)(m0 + m) * DDIM;
            float*       rrow = &Rt[m * 260];
#pragma unroll 4
            for (int q = 0; q < 16; ++q) {
                int d = ds + q * 4;
                float4 e4 = *(const float4*)(erow + d);
                float4 r4 = *(const float4*)(rrow + d);
                float qv[4] = {e4.x, e4.y, e4.z, e4.w};
                float rv[4] = {r4.x, r4.y, r4.z, r4.w};
                float rn[4];
#pragma unroll
                for (int t = 0; t < 4; ++t) {
                    float d1  = qv[t] - rv[t];   // fl(q - r)  (loss term)
                    float qst = rv[t] + d1;      // fl(r + d1) (straight-through)
                    rn[t]     = rv[t] - qst;     // fl(r - q_st)
                    lacc = fmaf(d1, d1, lacc);
                }
                *(float4*)(rrow + d) = make_float4(rn[0], rn[1], rn[2], rn[3]);
                if (l == LLAY - 1) {
                    float4 x4 = *(const float4*)(xrow + d);
                    *(float4*)(orow + d) =
                        make_float4(x4.x - rn[0], x4.y - rn[1], x4.z - rn[2], x4.w - rn[3]);
                }
            }
        }
    }

    // ---- loss reduction: wave -> block -> global atomic ----
    // waves 4..7 carry exact 0.0f; adding them preserves the sum bitwise.
#pragma unroll
    for (int off = 32; off > 0; off >>= 1) lacc += __shfl_down(lacc, off, 64);
    __syncthreads();
    if ((tid & 63) == 0) lred[tid >> 6] = lacc;
    __syncthreads();
    if (tid == 0) {
        float t = ((((((lred[0] + lred[1]) + lred[2]) + lred[3]) + lred[4])
                    + lred[5]) + lred[6]) + lred[7];
        atomicAdd(out + LOSS_OFF, t * (0.25f / 16777216.0f));
    }
}

// ---------------------------------------------------------------------------
extern "C" void kernel_launch(void* const* d_in, const int* in_sizes, int n_in,
                              void* d_out, int out_size, void* d_ws, size_t ws_size,
                              hipStream_t stream) {
    const float* x  = (const float*)d_in[0];
    const float* E  = (const float*)d_in[1];
    float* out = (float*)d_out;
    _Float16* Eh = (_Float16*)d_ws;
    float* ekkp = (float*)((char*)d_ws + EKK_BYTE_OFF);   // needs ~8.42 MB ws

    rvq_prep16<<<dim3(1024), dim3(256), 0, stream>>>(E, Eh, out);
    rvq_ekk<<<dim3(32), dim3(256), 0, stream>>>(E, ekkp);
    rvq_main<<<dim3(1024), dim3(512), 0, stream>>>(x, E, Eh, ekkp, out);
}

// Round 6
// 1253.329 us; speedup vs baseline: 1.7110x; 1.5268x over previous
//
#include <hip/hip_runtime.h>
#include <math.h>

// Problem constants (fixed by the reference setup)
#define NTOK  65536      // B*T = 16*4096
#define DDIM  256
#define KCODE 1024
#define LLAY  8
#define NQ    (NTOK*DDIM)        // 16777216 floats: quantized output
#define LOSS_OFF NQ              // 1 float: total loss
#define IDX_OFF  (NQ+1)          // 524288 floats: indices [B,T,L] as float

// ws layout (bytes):
//   [0, 4MB)     Eh16: f16 codebook, SWIZZLED into MFMA B-fragment order:
//                element (((l*64 + t)*8 + ks)*64 + lane)*8 + j
//                  = E[l][t*16 + (lane&15)][ks*32 + (lane>>4)*8 + j]  (f16 RTNE)
//   [8MB, +32KB) ekk   f32  [l][k]  = ||e||^2 (f64-accumulated, narrowed)
#define EKK_BYTE_OFF 8388608

typedef __attribute__((ext_vector_type(8))) _Float16 half8;  // 8 f16 (4 VGPR)
typedef __attribute__((ext_vector_type(4))) float f32x4;     // MFMA C/D frag

// ---------------------------------------------------------------------------
// Prep kernel A: E f32 -> f16, swizzled MFMA B-fragment order.
// One thread per (l, t, ks, lane): 8*64*8*64 = 262144 threads.
// ---------------------------------------------------------------------------
__global__ __launch_bounds__(256) void rvq_prep16(const float* __restrict__ E,
                                                  _Float16* __restrict__ Eh,
                                                  float* __restrict__ out) {
    int gid  = blockIdx.x * 256 + threadIdx.x;   // 1024 blocks * 256
    int lane = gid & 63;
    int ks   = (gid >> 6) & 7;
    int t    = (gid >> 9) & 63;
    int l    = gid >> 15;
    int code = t * 16 + (lane & 15);
    int d    = ks * 32 + (lane >> 4) * 8;
    const float* src = E + ((size_t)(l * KCODE + code)) * DDIM + d;
    float4 a = *(const float4*)(src);
    float4 b = *(const float4*)(src + 4);
    float f[8] = {a.x, a.y, a.z, a.w, b.x, b.y, b.z, b.w};
    half8 h;
#pragma unroll
    for (int j = 0; j < 8; ++j) h[j] = (_Float16)f[j];   // RTNE
    *(half8*)(Eh + (size_t)gid * 8) = h;
    if (gid == 0) out[LOSS_OFF] = 0.0f;
}

// ---------------------------------------------------------------------------
// Prep kernel B: per-code ||e||^2 (f32 squares, f64 accumulate, narrow).
// ---------------------------------------------------------------------------
__global__ __launch_bounds__(256) void rvq_ekk(const float* __restrict__ E,
                                               float* __restrict__ ekk) {
    int gid = blockIdx.x * 256 + threadIdx.x;   // 8192 = L*K
    const float4* rowp = (const float4*)(E + (size_t)gid * DDIM);
    double s = 0.0;
#pragma unroll 8
    for (int i = 0; i < 64; ++i) {
        float4 v = rowp[i];
        float p0 = v.x * v.x, p1 = v.y * v.y, p2 = v.z * v.z, p3 = v.w * v.w;
        s += (double)p0; s += (double)p1; s += (double)p2; s += (double)p3;
    }
    ekk[gid] = (float)s;
}

// ---------------------------------------------------------------------------
// top-2 merge with (score, index) lexicographic order (np.argmin ties)
// ---------------------------------------------------------------------------
__device__ __forceinline__ void merge2(float& s1, int& k1, float& s2, int& k2,
                                       float ps1, int pk1, float ps2, int pk2) {
    bool pb = (ps1 < s1) || (ps1 == s1 && pk1 < k1);
    if (pb) {
        bool mb = (s1 < ps2) || (s1 == ps2 && k1 < pk2);
        float ns2 = mb ? s1 : ps2; int nk2 = mb ? k1 : pk2;
        s1 = ps1; k1 = pk1; s2 = ns2; k2 = nk2;
    } else {
        bool mb = (ps1 < s2) || (ps1 == s2 && pk1 < k2);
        if (mb) { s2 = ps1; k2 = pk1; }
    }
}

// ---------------------------------------------------------------------------
// Main kernel: 64 tokens/block, 4 waves (R2 chassis).
//   wave w: token-half th=w&1 (32 tokens, 2 MFMA tiles), code-half ch=w>>1.
//   SINGLE-PASS f16 MFMA scoring (validated end-to-end in round 4: f16 approx
//   error ~1.6e-5 << top-candidate score gaps ~1e-3; exact f32 rescore of the
//   4 candidates decides the winner bitwise) -> per-lane top-2 -> lane merge
//   -> 4 candidates/token -> exact f32-chain rescore -> winner -> residual
//   update in LDS (exact straight-through f32 ops).
//   B streams linearly through a 4-slot register rotation (3-step lead);
//   prefetch step index is CLAMPED to the stream end (min(step,255)) so every
//   global read is strictly in-bounds; clamped steps only fill slots that are
//   never consumed, so numerics are unchanged.
// ---------------------------------------------------------------------------
__global__ __launch_bounds__(256, 2) void rvq_main(const float* __restrict__ x,
                                                   const float* __restrict__ E,
                                                   const _Float16* __restrict__ Eh,
                                                   const float* __restrict__ ekk,
                                                   float* __restrict__ out) {
    __shared__ __align__(16) float  Rt[64 * 260];   // residual f32 [tok][260pad]
    __shared__ double Ad[256];                      // A_n partial sums
    __shared__ float4 cand[128];                    // [tok][ch]: s1,k1,s2,k2
    __shared__ float  Af[64];                       // per-token ||r||^2 (f32)
    __shared__ int    kw[64];                       // winning code per token
    __shared__ float  lred[4];                      // per-wave loss partials

    const int tid  = threadIdx.x;
    const int lane = tid & 63;
    const int wv   = tid >> 6;
    const int th   = wv & 1;       // token half
    const int ch   = wv >> 1;      // code half
    const int col  = lane & 15;    // MFMA n / m index within tile
    const int quad = lane >> 4;    // MFMA k-chunk selector
    const int m0   = blockIdx.x * 64;

    // ---- load residual = x into LDS (row-major, pad 260) ----
#pragma unroll
    for (int u = 0; u < 16; ++u) {
        int id4 = u * 256 + tid;          // 4096 float4
        int mm  = id4 >> 6;
        int d4  = (id4 & 63) << 2;
        float4 v = *(const float4*)(x + (size_t)(m0 + mm) * DDIM + d4);
        *(float4*)(&Rt[mm * 260 + d4]) = v;
    }

    float lacc = 0.f;

    for (int l = 0; l < LLAY; ++l) {
        const float* El = E + (size_t)l * KCODE * DDIM;
        __syncthreads();   // Rt stable (prev layer update done)

        // ---- A_m = sum_d fl32(r^2), f64-accurate, narrowed to f32 ----
        {
            int m = tid >> 2, c = tid & 3;
            const float* rr = &Rt[m * 260 + c * 64];
            double sa = 0.0;
#pragma unroll 4
            for (int q = 0; q < 16; ++q) {
                float4 v = *(const float4*)(rr + q * 4);
                float p0 = v.x * v.x, p1 = v.y * v.y, p2 = v.z * v.z, p3 = v.w * v.w;
                sa += (double)p0; sa += (double)p1; sa += (double)p2; sa += (double)p3;
            }
            Ad[tid] = sa;
        }
        __syncthreads();
        if (tid < 64) {
            double a = Ad[tid * 4] + Ad[tid * 4 + 1] + Ad[tid * 4 + 2] + Ad[tid * 4 + 3];
            Af[tid] = (float)a;
        }
        __syncthreads();

        // ---- per-lane A values for the 8 (tile,reg) accumulator rows ----
        float Ai[2][4];
#pragma unroll
        for (int tt = 0; tt < 2; ++tt)
#pragma unroll
            for (int g = 0; g < 4; ++g)
                Ai[tt][g] = Af[th * 32 + tt * 16 + quad * 4 + g];

        // ---- build A-frag cache (f16) for this wave's 2 tiles ----
        half8 ah[2][8];
#pragma unroll
        for (int tt = 0; tt < 2; ++tt) {
            const float* rrow = &Rt[(th * 32 + tt * 16 + col) * 260];
#pragma unroll
            for (int ks = 0; ks < 8; ++ks) {
                float4 p = *(const float4*)(rrow + ks * 32 + quad * 8);
                float4 q = *(const float4*)(rrow + ks * 32 + quad * 8 + 4);
                float f[8] = {p.x, p.y, p.z, p.w, q.x, q.y, q.z, q.w};
#pragma unroll
                for (int j = 0; j < 8; ++j) ah[tt][ks][j] = (_Float16)f[j];
            }
        }

        // ---- approx scoring: 32 code-tiles of 16, top-2 per lane-stream ----
        // tp packs (tc2<<8 | tc1); tile-codes are 5-bit, 0xff = sentinel
        // (sentinel never survives: all 32 real scores are finite).
        float ts1[2][4], ts2[2][4];
        int   tp[2][4];
#pragma unroll
        for (int tt = 0; tt < 2; ++tt)
#pragma unroll
            for (int g = 0; g < 4; ++g) {
                ts1[tt][g] = INFINITY; ts2[tt][g] = INFINITY; tp[tt][g] = 0xffff;
            }

        const int co = ch * 512;
        // linear swizzled stream for this (l,ch): 256 steps of 512 halfs (1KB)
        const _Float16* pstream =
            Eh + ((size_t)(l * 64 + ch * 32) * 4096) + (size_t)lane * 8;
        const float* ekbase = ekk + l * KCODE + co + col;

        // 4-slot rotation, 3-step prefetch lead. Slot (s%4) holds step s.
        half8 BH[4];
        BH[0] = *(const half8*)(pstream);
        BH[1] = *(const half8*)(pstream + 512);
        BH[2] = *(const half8*)(pstream + 1024);

        for (int c = 0; c < 32; ++c) {
            float ekv = ekbase[c * 16];

            f32x4 acc0 = {0.f, 0.f, 0.f, 0.f};
            f32x4 acc1 = {0.f, 0.f, 0.f, 0.f};
#pragma unroll
            for (int ks = 0; ks < 8; ++ks) {
                const int pf = (ks + 3) & 3;     // prefetch slot (compile-time)
                const int cs = ks & 3;           // consume slot (compile-time)
                // prefetch step c*8+ks+3, clamped to the last step (255) so the
                // read is always in-bounds; clamped steps land only in slots
                // that are never consumed (they'd belong to c >= 32).
                int sp = c * 8 + ks + 3;
                sp = sp > 255 ? 255 : sp;
                BH[pf] = *(const half8*)(pstream + (size_t)sp * 512);
                acc0 = __builtin_amdgcn_mfma_f32_16x16x32_f16(ah[0][ks], BH[cs], acc0, 0, 0, 0);
                acc1 = __builtin_amdgcn_mfma_f32_16x16x32_f16(ah[1][ks], BH[cs], acc1, 0, 0, 0);
            }

#pragma unroll
            for (int tt = 0; tt < 2; ++tt)
#pragma unroll
                for (int g = 0; g < 4; ++g) {
                    float v = tt ? acc1[g] : acc0[g];
                    float s = fmaf(-2.f, v, Ai[tt][g] + ekv);
                    if (s < ts1[tt][g]) {
                        ts2[tt][g] = ts1[tt][g];
                        tp[tt][g]  = ((tp[tt][g] & 0xff) << 8) | c;
                        ts1[tt][g] = s;
                    } else if (s < ts2[tt][g]) {
                        ts2[tt][g] = s;
                        tp[tt][g]  = (tp[tt][g] & 0xff) | (c << 8);
                    }
                }
        }

        // ---- convert tile-codes to global code indices ----
        int ik1[2][4], ik2[2][4];
#pragma unroll
        for (int tt = 0; tt < 2; ++tt)
#pragma unroll
            for (int g = 0; g < 4; ++g) {
                ik1[tt][g] = co + ((tp[tt][g] & 0xff) << 4) + col;
                ik2[tt][g] = co + (((tp[tt][g] >> 8) & 0xff) << 4) + col;
            }

        // ---- merge top-2 across the 16 cols (lanes differing in bits 0..3) ----
#pragma unroll
        for (int off = 1; off <= 8; off <<= 1) {
#pragma unroll
            for (int tt = 0; tt < 2; ++tt)
#pragma unroll
                for (int g = 0; g < 4; ++g) {
                    float os1 = __shfl_xor(ts1[tt][g], off, 64);
                    int   ok1 = __shfl_xor(ik1[tt][g], off, 64);
                    float os2 = __shfl_xor(ts2[tt][g], off, 64);
                    int   ok2 = __shfl_xor(ik2[tt][g], off, 64);
                    merge2(ts1[tt][g], ik1[tt][g], ts2[tt][g], ik2[tt][g],
                           os1, ok1, os2, ok2);
                }
        }
        if (col == 0) {
#pragma unroll
            for (int tt = 0; tt < 2; ++tt)
#pragma unroll
                for (int g = 0; g < 4; ++g) {
                    int tokl = th * 32 + tt * 16 + quad * 4 + g;
                    cand[tokl * 2 + ch] = make_float4(ts1[tt][g], __int_as_float(ik1[tt][g]),
                                                      ts2[tt][g], __int_as_float(ik2[tt][g]));
                }
        }
        __syncthreads();

        // ---- exact f32 rescore of the 4 candidates (bitwise np semantics) ----
        {
            int m = tid >> 2, j = tid & 3;
            float4 cd = cand[m * 2 + (j >> 1)];
            int myk = (j & 1) ? __float_as_int(cd.w) : __float_as_int(cd.y);
            const float* erow = El + (size_t)myk * DDIM;
            const float* rrow = &Rt[m * 260];
            float M = 0.f;
#pragma unroll 8
            for (int q = 0; q < 64; ++q) {     // ascending-d single fma chain
                float4 e4 = *(const float4*)(erow + q * 4);
                float4 r4 = *(const float4*)(rrow + q * 4);
                M = fmaf(r4.x, e4.x, M);
                M = fmaf(r4.y, e4.y, M);
                M = fmaf(r4.z, e4.z, M);
                M = fmaf(r4.w, e4.w, M);
            }
            float u = Af[m] + ekk[l * KCODE + myk];   // fl32(A + B)
            float s = fmaf(-2.f, M, u);               // fl32(u - 2M)
#pragma unroll
            for (int off = 1; off <= 2; off <<= 1) {
                float os = __shfl_xor(s, off, 64);
                int   ok = __shfl_xor(myk, off, 64);
                if ((os < s) || (os == s && ok < myk)) { s = os; myk = ok; }
            }
            if (j == 0) {
                kw[m] = myk;
                out[IDX_OFF + (size_t)(m0 + m) * LLAY + l] = (float)myk;
            }
        }
        __syncthreads();

        // ---- residual update (exact straight-through f32 ops) + loss ----
        {
            int m  = tid >> 2;
            int ds = (tid & 3) * 64;
            int kwm = kw[m];
            const float* erow = El + (size_t)kwm * DDIM;
            const float* xrow = x  + (size_t)(m0 + m) * DDIM;
            float*       orow = out + (size_t)(m0 + m) * DDIM;
            float*       rrow = &Rt[m * 260];
#pragma unroll 4
            for (int q = 0; q < 16; ++q) {
                int d = ds + q * 4;
                float4 e4 = *(const float4*)(erow + d);
                float4 r4 = *(const float4*)(rrow + d);
                float qv[4] = {e4.x, e4.y, e4.z, e4.w};
                float rv[4] = {r4.x, r4.y, r4.z, r4.w};
                float rn[4];
#pragma unroll
                for (int t = 0; t < 4; ++t) {
                    float d1  = qv[t] - rv[t];   // fl(q - r)  (loss term)
                    float qst = rv[t] + d1;      // fl(r + d1) (straight-through)
                    rn[t]     = rv[t] - qst;     // fl(r - q_st)
                    lacc = fmaf(d1, d1, lacc);
                }
                *(float4*)(rrow + d) = make_float4(rn[0], rn[1], rn[2], rn[3]);
                if (l == LLAY - 1) {
                    float4 x4 = *(const float4*)(xrow + d);
                    *(float4*)(orow + d) =
                        make_float4(x4.x - rn[0], x4.y - rn[1], x4.z - rn[2], x4.w - rn[3]);
                }
            }
        }
    }

    // ---- loss reduction: wave -> block -> global atomic ----
#pragma unroll
    for (int off = 32; off > 0; off >>= 1) lacc += __shfl_down(lacc, off, 64);
    __syncthreads();
    if ((tid & 63) == 0) lred[tid >> 6] = lacc;
    __syncthreads();
    if (tid == 0) {
        float t = lred[0] + lred[1] + lred[2] + lred[3];
        atomicAdd(out + LOSS_OFF, t * (0.25f / 16777216.0f));
    }
}

// ---------------------------------------------------------------------------
extern "C" void kernel_launch(void* const* d_in, const int* in_sizes, int n_in,
                              void* d_out, int out_size, void* d_ws, size_t ws_size,
                              hipStream_t stream) {
    const float* x  = (const float*)d_in[0];
    const float* E  = (const float*)d_in[1];
    float* out = (float*)d_out;
    _Float16* Eh = (_Float16*)d_ws;
    float* ekkp = (float*)((char*)d_ws + EKK_BYTE_OFF);   // needs ~8.42 MB ws

    rvq_prep16<<<dim3(1024), dim3(256), 0, stream>>>(E, Eh, out);
    rvq_ekk<<<dim3(32), dim3(256), 0, stream>>>(E, ekkp);
    rvq_main<<<dim3(1024), dim3(256), 0, stream>>>(x, E, Eh, ekkp, out);
}